// Round 6
// baseline (114074.878 us; speedup 1.0000x reference)
//
#include <hip/hip_runtime.h>
#include <hip/hip_bf16.h>
#include <stdint.h>

#define NS 4096     // samples / time steps
#define DT 1024     // dim_t == hidden == in
#define H4 4096     // 4*HID

// ---------- math helpers ----------
__device__ __forceinline__ float sigm_f(float x) { return 1.f / (1.f + __expf(-x)); }
__device__ __forceinline__ float tanh_f(float x) {
    float ax = fminf(fabsf(x), 15.f);                 // overflow-safe
    float t = 1.f - 2.f / (__expf(2.f * ax) + 1.f);
    return copysignf(t, x);
}

// ---------- sinusoidal embedding ----------
__global__ void emb_kernel(const int* __restrict__ ts, float* __restrict__ emb) {
    int t = blockIdx.x;
    int i = threadIdx.x;                 // 0..511
    float tv = (float)ts[t];
    const float c = -0.018024149455922082f;  // -ln(10000)/511
    float f = __expf(c * (float)i);
    float a = tv * f;
    float s, co;
    sincosf(a, &s, &co);
    emb[(size_t)t * DT + i] = s;
    emb[(size_t)t * DT + 512 + i] = co;
}

// ---------- generic C = A(M,K) @ B(Nc,K)^T + bias [+bias2] [+skip] [silu] ----------
// BM=128, BN=64, BK=16, 256 threads, each thread 8x4 outputs.
// XGMODE: 0 = plain fp32 C; 1 = bf16 XG layout; 2 = fp32 XG layout.
// XG layout per epoch (4096 elems): pos = k*16 + r*4 + q for col = q*1024 + 4k + r.
template <bool SILU, bool SKIP, int XGMODE>
__global__ __launch_bounds__(256) void gemm_bt(
    const float* __restrict__ A, const float* __restrict__ B,
    const float* __restrict__ bias, const float* __restrict__ bias2,
    const float* __restrict__ skip, float* __restrict__ Cf,
    __hip_bfloat16* __restrict__ Cb, int M, int Nc, int K)
{
    __shared__ __align__(16) float As[16][132];
    __shared__ __align__(16) float Bs[16][68];
    const int bn = blockIdx.x, bm = blockIdx.y, lz = blockIdx.z;
    if (XGMODE) {
        B     += (size_t)lz * H4 * DT;
        bias  += (size_t)lz * H4;
        bias2 += (size_t)lz * H4;
    }
    const int tid = threadIdx.x;
    const int tr = tid >> 4, tc = tid & 15;
    const int alr = tid >> 1, alc = (tid & 1) << 3;   // A: 128 rows x 16 cols
    const int blr = tid >> 2, blc = (tid & 3) << 2;   // B: 64 rows x 16 cols
    const float* Ap = A + (size_t)(bm * 128 + alr) * K + alc;
    const float* Bp = B + (size_t)(bn * 64 + blr) * K + blc;

    float acc[8][4];
#pragma unroll
    for (int i = 0; i < 8; i++)
#pragma unroll
        for (int j = 0; j < 4; j++) acc[i][j] = 0.f;

    for (int kk = 0; kk < K; kk += 16) {
        float4 a0 = *(const float4*)(Ap + kk);
        float4 a1 = *(const float4*)(Ap + kk + 4);
        float4 b0 = *(const float4*)(Bp + kk);
        __syncthreads();
        As[alc + 0][alr] = a0.x; As[alc + 1][alr] = a0.y;
        As[alc + 2][alr] = a0.z; As[alc + 3][alr] = a0.w;
        As[alc + 4][alr] = a1.x; As[alc + 5][alr] = a1.y;
        As[alc + 6][alr] = a1.z; As[alc + 7][alr] = a1.w;
        Bs[blc + 0][blr] = b0.x; Bs[blc + 1][blr] = b0.y;
        Bs[blc + 2][blr] = b0.z; Bs[blc + 3][blr] = b0.w;
        __syncthreads();
#pragma unroll
        for (int k = 0; k < 16; k++) {
            const float4 av0 = *(const float4*)&As[k][tr * 8];
            const float4 av1 = *(const float4*)&As[k][tr * 8 + 4];
            const float4 bv  = *(const float4*)&Bs[k][tc * 4];
            float aa[8] = {av0.x, av0.y, av0.z, av0.w, av1.x, av1.y, av1.z, av1.w};
            float bb[4] = {bv.x, bv.y, bv.z, bv.w};
#pragma unroll
            for (int i = 0; i < 8; i++)
#pragma unroll
                for (int j = 0; j < 4; j++)
                    acc[i][j] = fmaf(aa[i], bb[j], acc[i][j]);
        }
    }

#pragma unroll
    for (int i = 0; i < 8; i++) {
        int row = bm * 128 + tr * 8 + i;
#pragma unroll
        for (int j = 0; j < 4; j++) {
            int col = bn * 64 + tc * 4 + j;
            float v = acc[i][j] + bias[col];
            if (XGMODE) v += bias2[col];
            if (SKIP)   v += skip[(size_t)row * Nc + col];
            if (SILU)   v = v * (1.f / (1.f + __expf(-v)));
            if (XGMODE) {
                int q = col >> 10, jj = col & 1023;
                size_t idx = (size_t)row * 16384 + (size_t)lz * 4096
                           + ((size_t)(jj >> 2) << 4) + ((jj & 3) << 2) + q;
                if (XGMODE == 2) Cf[idx] = v;
                else             Cb[idx] = __float2bfloat16(v);
            } else {
                Cf[(size_t)row * Nc + col] = v;
            }
        }
    }
}

// ---------- persistent sequential LSTM chain ----------
// 64 WGs x 1024 threads (16 waves; 1 block/CU on 64 CUs). Wave w of WG k
// owns hidden row 16k+w and computes all 4 gates of that row.
// Evidence trail:
//   r2: wave-local dot killed bank conflicts (1.7e7 -> 0); per-wave 8B
//       publishes (4 same-line fabric transactions) cost +2700cy/epoch
//       => ~700cy per serialized same-line transaction at the coherence pt.
//   r3: coalesced 32B publish restored WRITE_SIZE (557->164MB, predicted).
//   r5: sleep backoff AND fold reduction both NULL (47.3 -> 47.4ms, FETCH
//       unchanged) => poll rate and LDS-pipe are NOT binding. Per-epoch
//       TCC leakage ~45KB ~= 8 XCDs x 8KB => polls served from local L2.
//   Remaining big serialized term: each 128B hbuf line was written by 4
//   DIFFERENT WGs (4 XCDs) per epoch = ~4x700cy same-line write churn.
// r6: single-writer single-transaction full-line publish. WG k owns rows
// 16k..16k+15 = one line-aligned 128B hbuf region; threads t<16 publish it
// as ONE wave-coalesced 128B store (r2->r3 WRITE_SIZE behavior proved
// contiguous lane atomics coalesce). Writers/line 4 -> 1; full-line write
// needs no ownership read. Each thread polls exactly 1 word. No sleep.
// Mailbox safety: mbox[w]@e+1 written only after wave w passed its poll of
// epoch e, which requires all WGs published e, which requires wave 0
// consumed mbox[w]@e. Tags strictly increase; slots zeroed before first B1.
// hbuf parity safety: slot for epoch e overwritten only at e+2 (invariant
// inherited from the harness-verified round-0 kernel).
template <typename XT>
__global__ __launch_bounds__(1024, 1) void seq_kernel(
    const float* __restrict__ Whh,            // [4][4096][1024]
    const XT* __restrict__ XG,                // [epoch][kk*16 + r*4 + q]
    float* __restrict__ hall,                 // [4096][1024]
    uint64_t* hbuf)                           // [2][1024]
{
    const int k = blockIdx.x;                 // 0..63
    const int t = threadIdx.x;                // 0..1023
    const int w = t >> 6;                     // wave id 0..15
    const int lam = t & 63;                   // lane id
    const int row = (k << 4) + w;             // hidden row owned by this wave

    // wreg[l][q][i*4+e] = Whh[l][q*1024+row][256*i + 4*lam + e]
    float wreg[4][4][16];
#pragma unroll
    for (int l = 0; l < 4; l++)
#pragma unroll
        for (int q = 0; q < 4; q++) {
            const float* src = Whh + ((size_t)l * H4 + q * 1024 + row) * 1024 + (lam << 2);
#pragma unroll
            for (int i = 0; i < 4; i++) {
                float4 v = *(const float4*)(src + (i << 8));
                wreg[l][q][i * 4 + 0] = v.x;
                wreg[l][q][i * 4 + 1] = v.y;
                wreg[l][q][i * 4 + 2] = v.z;
                wreg[l][q][i * 4 + 3] = v.w;
            }
        }

    __shared__ __align__(16) float lh[2][1024];   // epoch-parity double buffer
    __shared__ __align__(8) uint64_t mbox[16];    // per-wave publish mailbox
    if (t < 16) mbox[t] = 0;                      // ordered by first B1
    float creg = 0.f;                             // c for this wave's row (all lanes)

    const bool b1 = (lam & 1) != 0, b2 = (lam & 2) != 0;

    for (int step = 0; step < NS; ++step) {
#pragma unroll
        for (int l = 0; l < 4; l++) {
            const int it = step * 4 + l + 1;             // epoch being produced
            const uint32_t rtag = (uint32_t)(it - 1);
            uint64_t* rb = ((it - 1) & 1) ? (hbuf + 1024) : hbuf;
            uint64_t* wb = (it & 1) ? (hbuf + 1024) : hbuf;
            float* pb = lh[(it - 1) & 1];

            // ---- XG prefetch (wave-uniform address -> broadcast load),
            //      issued before polling so latency hides under the wait.
            //      row 16k+w: kk = 4k + (w>>2), r = w&3
            //      pos(q) = kk*16 + r*4 + q -> base = 64k + 16*(w>>2) + 4*(w&3)
            float xg0, xg1, xg2, xg3;
            {
                const XT* p = XG + (size_t)(it - 1) * H4
                            + (k << 6) + ((w >> 2) << 4) + ((w & 3) << 2);
                if constexpr (sizeof(XT) == 4) {
                    float4 v = *(const float4*)p;
                    xg0 = v.x; xg1 = v.y; xg2 = v.z; xg3 = v.w;
                } else {
                    ushort4 v = *(const ushort4*)p;
                    xg0 = __uint_as_float((uint32_t)v.x << 16);
                    xg1 = __uint_as_float((uint32_t)v.y << 16);
                    xg2 = __uint_as_float((uint32_t)v.z << 16);
                    xg3 = __uint_as_float((uint32_t)v.w << 16);
                }
            }

            // ---- poll + stage: thread t owns exactly word t
            {
                uint64_t u;
                do {
                    u = __hip_atomic_load(&rb[t],
                                          __ATOMIC_RELAXED, __HIP_MEMORY_SCOPE_AGENT);
                } while ((uint32_t)u != rtag);
                pb[t] = __uint_as_float((uint32_t)(u >> 32));
            }
            __syncthreads();   // B1: lh[parity] complete (also orders mbox init/reuse)

            // ---- wave-local dot: all 4 gates of this wave's row
            float a0 = 0.f, a1 = 0.f, a2 = 0.f, a3 = 0.f;
#pragma unroll
            for (int i = 0; i < 4; i++) {
                const float4 hv = *(const float4*)(pb + (i << 8) + (lam << 2));
                a0 = fmaf(wreg[l][0][i * 4 + 0], hv.x, a0);
                a0 = fmaf(wreg[l][0][i * 4 + 1], hv.y, a0);
                a0 = fmaf(wreg[l][0][i * 4 + 2], hv.z, a0);
                a0 = fmaf(wreg[l][0][i * 4 + 3], hv.w, a0);
                a1 = fmaf(wreg[l][1][i * 4 + 0], hv.x, a1);
                a1 = fmaf(wreg[l][1][i * 4 + 1], hv.y, a1);
                a1 = fmaf(wreg[l][1][i * 4 + 2], hv.z, a1);
                a1 = fmaf(wreg[l][1][i * 4 + 3], hv.w, a1);
                a2 = fmaf(wreg[l][2][i * 4 + 0], hv.x, a2);
                a2 = fmaf(wreg[l][2][i * 4 + 1], hv.y, a2);
                a2 = fmaf(wreg[l][2][i * 4 + 2], hv.z, a2);
                a2 = fmaf(wreg[l][2][i * 4 + 3], hv.w, a2);
                a3 = fmaf(wreg[l][3][i * 4 + 0], hv.x, a3);
                a3 = fmaf(wreg[l][3][i * 4 + 1], hv.y, a3);
                a3 = fmaf(wreg[l][3][i * 4 + 2], hv.z, a3);
                a3 = fmaf(wreg[l][3][i * 4 + 3], hv.w, a3);
            }

            // ---- fold reduction: 10 DS ops (case-verified over all q=lam&3)
            {
                float x  = __shfl_xor(b1 ? a0 : a1, 1);
                float y  = __shfl_xor(b1 ? a2 : a3, 1);
                float na = (b1 ? a1 : a0) + x;
                float nb = (b1 ? a3 : a2) + y;
                float z  = __shfl_xor(b2 ? na : nb, 2);
                float nc = (b2 ? nb : na) + z;
                nc += __shfl_xor(nc, 4);
                nc += __shfl_xor(nc, 8);
                nc += __shfl_xor(nc, 16);
                nc += __shfl_xor(nc, 32);
                float g1 = __shfl_xor(nc, 1);       // gate q^1
                float g2 = __shfl_xor(nc, 2);       // gate q^2
                float g3 = __shfl_xor(g1, 2);       // gate q^3
                // variable m holds gate q^m; gate j lives at index j^q
                a0 = b1 ? (b2 ? g3 : g1) : (b2 ? g2 : nc);   // gate 0 (i)
                a1 = b1 ? (b2 ? g2 : nc) : (b2 ? g3 : g1);   // gate 1 (f)
                a2 = b1 ? (b2 ? g1 : g3) : (b2 ? nc : g2);   // gate 2 (g)
                a3 = b1 ? (b2 ? nc : g2) : (b2 ? g1 : g3);   // gate 3 (o)
            }

            // ---- gates on all lanes (redundant, no divergence)
            float gi = a0 + xg0, gf = a1 + xg1, gG = a2 + xg2, go = a3 + xg3;
            float cn = sigm_f(gf) * creg + sigm_f(gi) * tanh_f(gG);
            creg = cn;
            float hn = sigm_f(go) * tanh_f(cn);

            // ---- deposit in mailbox (per-wave lane 0)
            if (lam == 0) {
                uint64_t word = ((uint64_t)__float_as_uint(hn) << 32) | (uint64_t)(uint32_t)it;
                __hip_atomic_store(&mbox[w], word,
                                   __ATOMIC_RELAXED, __HIP_MEMORY_SCOPE_WORKGROUP);
            }

            // ---- wave 0 gathers + ONE coalesced 128B (full-line) publish
            if (t < 16) {
                uint64_t u;
                do {
                    u = __hip_atomic_load(&mbox[t],
                                          __ATOMIC_RELAXED, __HIP_MEMORY_SCOPE_WORKGROUP);
                } while ((uint32_t)u != (uint32_t)it);
                if (l == 3)
                    hall[(size_t)step * 1024 + (k << 4) + t] =
                        __uint_as_float((uint32_t)(u >> 32));
                __hip_atomic_store(&wb[(k << 4) + t], u,
                                   __ATOMIC_RELAXED, __HIP_MEMORY_SCOPE_AGENT);
            }
        }
    }
}

extern "C" void kernel_launch(void* const* d_in, const int* in_sizes, int n_in,
                              void* d_out, int out_size, void* d_ws, size_t ws_size,
                              hipStream_t stream)
{
    const float* x      = (const float*)d_in[0];
    const int*   ts     = (const int*)d_in[1];
    const float* proj_w = (const float*)d_in[2];
    const float* proj_b = (const float*)d_in[3];
    const float* te_w1  = (const float*)d_in[4];
    const float* te_b1  = (const float*)d_in[5];
    const float* te_w2  = (const float*)d_in[6];
    const float* te_b2  = (const float*)d_in[7];
    const float* Wih    = (const float*)d_in[8];
    const float* Whh    = (const float*)d_in[9];
    const float* bih    = (const float*)d_in[10];
    const float* bhh    = (const float*)d_in[11];
    const float* lin_w  = (const float*)d_in[12];
    const float* lin_b  = (const float*)d_in[13];
    float* out = (float*)d_out;

    char* ws = (char*)d_ws;
    const size_t MB16 = (size_t)NS * DT * 4;                    // 16 MiB
    float* bufA = (float*)ws;                                   // emb -> emb2 -> hall
    float* bufB = (float*)(ws + MB16);                          // h1 -> xp
    const size_t xg_f32_bytes  = (size_t)NS * 16384 * 4;        // 256 MiB
    const size_t xg_bf16_bytes = (size_t)NS * 16384 * 2;        // 128 MiB
    const bool use_f32_xg = ws_size >= 2 * MB16 + xg_f32_bytes + 16384 + 64;
    float*          XGf = (float*)(ws + 2 * MB16);
    __hip_bfloat16* XGb = (__hip_bfloat16*)(ws + 2 * MB16);
    uint64_t* hbuf = (uint64_t*)(ws + 2 * MB16 +
                                 (use_f32_xg ? xg_f32_bytes : xg_bf16_bytes));

    hipMemsetAsync(hbuf, 0, 2 * 1024 * sizeof(uint64_t), stream);

    // emb = sinusoidal(timesteps)
    emb_kernel<<<NS, 512, 0, stream>>>(ts, bufA);
    // h1 = silu(emb @ te_w1^T + te_b1)
    gemm_bt<true, false, 0><<<dim3(16, 32), 256, 0, stream>>>(
        bufA, te_w1, te_b1, nullptr, nullptr, bufB, nullptr, NS, DT, DT);
    // emb2 = h1 @ te_w2^T + te_b2
    gemm_bt<false, false, 0><<<dim3(16, 32), 256, 0, stream>>>(
        bufB, te_w2, te_b2, nullptr, nullptr, bufA, nullptr, NS, DT, DT);
    // xp = x @ proj_w^T + proj_b + emb2
    gemm_bt<false, true, 0><<<dim3(16, 32), 256, 0, stream>>>(
        x, proj_w, proj_b, nullptr, bufA, bufB, nullptr, NS, DT, DT);
    // XG[l] = xp @ Wih[l]^T + bih[l] + bhh[l]   (permuted layout), z = layer
    if (use_f32_xg) {
        gemm_bt<false, false, 2><<<dim3(64, 32, 4), 256, 0, stream>>>(
            bufB, Wih, bih, bhh, nullptr, XGf, nullptr, NS, H4, DT);
        seq_kernel<float><<<64, 1024, 0, stream>>>(Whh, XGf, bufA, hbuf);
    } else {
        gemm_bt<false, false, 1><<<dim3(64, 32, 4), 256, 0, stream>>>(
            bufB, Wih, bih, bhh, nullptr, nullptr, XGb, NS, H4, DT);
        seq_kernel<__hip_bfloat16><<<64, 1024, 0, stream>>>(Whh, XGb, bufA, hbuf);
    }
    // out = hall @ lin_w^T + lin_b
    gemm_bt<false, false, 0><<<dim3(16, 32), 256, 0, stream>>>(
        bufA, lin_w, lin_b, nullptr, nullptr, out, nullptr, NS, DT, DT);
}

// Round 7
// 46113.562 us; speedup vs baseline: 2.4738x; 2.4738x over previous
//
#include <hip/hip_runtime.h>
#include <hip/hip_bf16.h>
#include <stdint.h>

#define NS 4096     // samples / time steps
#define DT 1024     // dim_t == hidden == in
#define H4 4096     // 4*HID

// ---------- math helpers ----------
__device__ __forceinline__ float sigm_f(float x) { return 1.f / (1.f + __expf(-x)); }
__device__ __forceinline__ float tanh_f(float x) {
    float ax = fminf(fabsf(x), 15.f);                 // overflow-safe
    float t = 1.f - 2.f / (__expf(2.f * ax) + 1.f);
    return copysignf(t, x);
}

// ---------- sinusoidal embedding ----------
__global__ void emb_kernel(const int* __restrict__ ts, float* __restrict__ emb) {
    int t = blockIdx.x;
    int i = threadIdx.x;                 // 0..511
    float tv = (float)ts[t];
    const float c = -0.018024149455922082f;  // -ln(10000)/511
    float f = __expf(c * (float)i);
    float a = tv * f;
    float s, co;
    sincosf(a, &s, &co);
    emb[(size_t)t * DT + i] = s;
    emb[(size_t)t * DT + 512 + i] = co;
}

// ---------- generic C = A(M,K) @ B(Nc,K)^T + bias [+bias2] [+skip] [silu] ----------
// BM=128, BN=64, BK=16, 256 threads, each thread 8x4 outputs.
// XGMODE: 0 = plain fp32 C; 1 = bf16 XG layout; 2 = fp32 XG layout.
// XG layout per epoch (4096 elems): pos = k*16 + r*4 + q for col = q*1024 + 4k + r.
template <bool SILU, bool SKIP, int XGMODE>
__global__ __launch_bounds__(256) void gemm_bt(
    const float* __restrict__ A, const float* __restrict__ B,
    const float* __restrict__ bias, const float* __restrict__ bias2,
    const float* __restrict__ skip, float* __restrict__ Cf,
    __hip_bfloat16* __restrict__ Cb, int M, int Nc, int K)
{
    __shared__ __align__(16) float As[16][132];
    __shared__ __align__(16) float Bs[16][68];
    const int bn = blockIdx.x, bm = blockIdx.y, lz = blockIdx.z;
    if (XGMODE) {
        B     += (size_t)lz * H4 * DT;
        bias  += (size_t)lz * H4;
        bias2 += (size_t)lz * H4;
    }
    const int tid = threadIdx.x;
    const int tr = tid >> 4, tc = tid & 15;
    const int alr = tid >> 1, alc = (tid & 1) << 3;   // A: 128 rows x 16 cols
    const int blr = tid >> 2, blc = (tid & 3) << 2;   // B: 64 rows x 16 cols
    const float* Ap = A + (size_t)(bm * 128 + alr) * K + alc;
    const float* Bp = B + (size_t)(bn * 64 + blr) * K + blc;

    float acc[8][4];
#pragma unroll
    for (int i = 0; i < 8; i++)
#pragma unroll
        for (int j = 0; j < 4; j++) acc[i][j] = 0.f;

    for (int kk = 0; kk < K; kk += 16) {
        float4 a0 = *(const float4*)(Ap + kk);
        float4 a1 = *(const float4*)(Ap + kk + 4);
        float4 b0 = *(const float4*)(Bp + kk);
        __syncthreads();
        As[alc + 0][alr] = a0.x; As[alc + 1][alr] = a0.y;
        As[alc + 2][alr] = a0.z; As[alc + 3][alr] = a0.w;
        As[alc + 4][alr] = a1.x; As[alc + 5][alr] = a1.y;
        As[alc + 6][alr] = a1.z; As[alc + 7][alr] = a1.w;
        Bs[blc + 0][blr] = b0.x; Bs[blc + 1][blr] = b0.y;
        Bs[blc + 2][blr] = b0.z; Bs[blc + 3][blr] = b0.w;
        __syncthreads();
#pragma unroll
        for (int k = 0; k < 16; k++) {
            const float4 av0 = *(const float4*)&As[k][tr * 8];
            const float4 av1 = *(const float4*)&As[k][tr * 8 + 4];
            const float4 bv  = *(const float4*)&Bs[k][tc * 4];
            float aa[8] = {av0.x, av0.y, av0.z, av0.w, av1.x, av1.y, av1.z, av1.w};
            float bb[4] = {bv.x, bv.y, bv.z, bv.w};
#pragma unroll
            for (int i = 0; i < 8; i++)
#pragma unroll
                for (int j = 0; j < 4; j++)
                    acc[i][j] = fmaf(aa[i], bb[j], acc[i][j]);
        }
    }

#pragma unroll
    for (int i = 0; i < 8; i++) {
        int row = bm * 128 + tr * 8 + i;
#pragma unroll
        for (int j = 0; j < 4; j++) {
            int col = bn * 64 + tc * 4 + j;
            float v = acc[i][j] + bias[col];
            if (XGMODE) v += bias2[col];
            if (SKIP)   v += skip[(size_t)row * Nc + col];
            if (SILU)   v = v * (1.f / (1.f + __expf(-v)));
            if (XGMODE) {
                int q = col >> 10, jj = col & 1023;
                size_t idx = (size_t)row * 16384 + (size_t)lz * 4096
                           + ((size_t)(jj >> 2) << 4) + ((jj & 3) << 2) + q;
                if (XGMODE == 2) Cf[idx] = v;
                else             Cb[idx] = __float2bfloat16(v);
            } else {
                Cf[(size_t)row * Nc + col] = v;
            }
        }
    }
}

// ---------- persistent sequential LSTM chain ----------
// 256 WGs x 256 threads (1 block/CU). Wave w of WG k owns hidden row 4k+w
// and computes all 4 gates of that row (wave-local dot + 10-op fold).
// Evidence trail:
//   r2: wave-local dot killed bank conflicts (1.7e7 -> 0); 4 separate 8B
//       same-line agent stores cost +2700cy/epoch (~700cy per serialized
//       same-line transaction).
//   r3: coalesced 32B publish restored WRITE_SIZE (557->164MB, predicted).
//   r5: sleep backoff AND fold reduction both NULL => poll RATE and the
//       LDS pipe are not binding.
//   r6: 1024-thread single-writer attempt FAILED ON A HW CAP, theory
//       untested: regsPerBlock=131072 => 128 VGPR/thread at 1024 threads;
//       wreg (256 f32) spilled to scratch (VGPR_Count 64, FETCH 84.5GB).
//       Lesson: single-writer lines must be achieved at <=256 threads.
// r7: PRIVATE-LINE publish at the proven 256-thread shape. hbuf layout
// [2][256][16] u64: WG k's 4 rows occupy bytes 0..31 of its OWN 128B
// line-aligned region -> writers/line 4 -> 1, no cross-XCD same-line write
// interleave. Publish = ONE coalesced 32B store (threads t<4). Poll word
// for row m*256+t is (m<<10)+((t>>2)<<4)+(t&3) (4 lanes/line, coalesced
// groups). s_sleep dropped: r5 showed no congestion benefit and its 512cy
// granularity adds detect-tail.
// Mailbox safety: mbox[w]@e+1 written only after wave w passed its poll of
// epoch e, which requires all WGs published e, which requires wave 0
// consumed mbox[w]@e. Tags strictly increase; slots zeroed before first B1.
// hbuf parity safety: slot for epoch e overwritten only at e+2 (invariant
// inherited from the harness-verified round-0 kernel).
template <typename XT>
__global__ __launch_bounds__(256, 1) void seq_kernel(
    const float* __restrict__ Whh,            // [4][4096][1024]
    const XT* __restrict__ XG,                // [epoch][k*16 + r*4 + q]
    float* __restrict__ hall,                 // [4096][1024]
    uint64_t* hbuf)                           // [2][256][16]
{
    const int k = blockIdx.x;
    const int t = threadIdx.x;
    const int w = t >> 6;                     // wave id
    const int lam = t & 63;                   // lane id
    const int row = (k << 2) + w;             // hidden row owned by this wave

    // wreg[l][q][i*4+e] = Whh[l][q*1024+row][256*i + 4*lam + e]
    float wreg[4][4][16];
#pragma unroll
    for (int l = 0; l < 4; l++)
#pragma unroll
        for (int q = 0; q < 4; q++) {
            const float* src = Whh + ((size_t)l * H4 + q * 1024 + row) * 1024 + (lam << 2);
#pragma unroll
            for (int i = 0; i < 4; i++) {
                float4 v = *(const float4*)(src + (i << 8));
                wreg[l][q][i * 4 + 0] = v.x;
                wreg[l][q][i * 4 + 1] = v.y;
                wreg[l][q][i * 4 + 2] = v.z;
                wreg[l][q][i * 4 + 3] = v.w;
            }
        }

    __shared__ __align__(16) float lh[2][1024];   // epoch-parity double buffer
    __shared__ __align__(8) uint64_t mbox[4];     // per-wave publish mailbox
    if (t < 4) mbox[t] = 0;                       // ordered by first B1
    float creg = 0.f;                             // c for this wave's row (all lanes)

    const bool b1 = (lam & 1) != 0, b2 = (lam & 2) != 0;

    // poll word index for m-th staged row (row = m*256 + t):
    //   g = row>>2 = (m<<6)+(t>>2), r = row&3 = t&3 -> word g*16+r
    const int pw = ((t >> 2) << 4) + (t & 3);

    for (int step = 0; step < NS; ++step) {
#pragma unroll
        for (int l = 0; l < 4; l++) {
            const int it = step * 4 + l + 1;             // epoch being produced
            const uint32_t rtag = (uint32_t)(it - 1);
            uint64_t* rb = ((it - 1) & 1) ? (hbuf + 4096) : hbuf;
            uint64_t* wb = (it & 1) ? (hbuf + 4096) : hbuf;
            float* pb = lh[(it - 1) & 1];

            // ---- XG prefetch (wave-uniform address -> broadcast load),
            //      issued before polling so latency hides under the wait
            float xg0, xg1, xg2, xg3;
            {
                const XT* p = XG + (size_t)(it - 1) * H4 + (k << 4) + (w << 2);
                if constexpr (sizeof(XT) == 4) {
                    float4 v = *(const float4*)p;
                    xg0 = v.x; xg1 = v.y; xg2 = v.z; xg3 = v.w;
                } else {
                    ushort4 v = *(const ushort4*)p;
                    xg0 = __uint_as_float((uint32_t)v.x << 16);
                    xg1 = __uint_as_float((uint32_t)v.y << 16);
                    xg2 = __uint_as_float((uint32_t)v.z << 16);
                    xg3 = __uint_as_float((uint32_t)v.w << 16);
                }
            }

            // ---- cooperative poll + stage (thread t stages rows m*256+t)
            uint32_t got = 0;
            while (got != 0xFu) {
#pragma unroll
                for (int m = 0; m < 4; m++) {
                    if (!(got & (1u << m))) {
                        uint64_t u = __hip_atomic_load(&rb[(m << 10) + pw],
                                                       __ATOMIC_RELAXED, __HIP_MEMORY_SCOPE_AGENT);
                        if ((uint32_t)u == rtag) {
                            pb[(m << 8) + t] = __uint_as_float((uint32_t)(u >> 32));
                            got |= (1u << m);
                        }
                    }
                }
            }
            __syncthreads();   // B1: lh[parity] complete (also orders mbox init/reuse)

            // ---- wave-local dot: all 4 gates of this wave's row
            float a0 = 0.f, a1 = 0.f, a2 = 0.f, a3 = 0.f;
#pragma unroll
            for (int i = 0; i < 4; i++) {
                const float4 hv = *(const float4*)(pb + (i << 8) + (lam << 2));
                a0 = fmaf(wreg[l][0][i * 4 + 0], hv.x, a0);
                a0 = fmaf(wreg[l][0][i * 4 + 1], hv.y, a0);
                a0 = fmaf(wreg[l][0][i * 4 + 2], hv.z, a0);
                a0 = fmaf(wreg[l][0][i * 4 + 3], hv.w, a0);
                a1 = fmaf(wreg[l][1][i * 4 + 0], hv.x, a1);
                a1 = fmaf(wreg[l][1][i * 4 + 1], hv.y, a1);
                a1 = fmaf(wreg[l][1][i * 4 + 2], hv.z, a1);
                a1 = fmaf(wreg[l][1][i * 4 + 3], hv.w, a1);
                a2 = fmaf(wreg[l][2][i * 4 + 0], hv.x, a2);
                a2 = fmaf(wreg[l][2][i * 4 + 1], hv.y, a2);
                a2 = fmaf(wreg[l][2][i * 4 + 2], hv.z, a2);
                a2 = fmaf(wreg[l][2][i * 4 + 3], hv.w, a2);
                a3 = fmaf(wreg[l][3][i * 4 + 0], hv.x, a3);
                a3 = fmaf(wreg[l][3][i * 4 + 1], hv.y, a3);
                a3 = fmaf(wreg[l][3][i * 4 + 2], hv.z, a3);
                a3 = fmaf(wreg[l][3][i * 4 + 3], hv.w, a3);
            }

            // ---- fold reduction: 10 DS ops (case-verified over all q=lam&3)
            {
                float x  = __shfl_xor(b1 ? a0 : a1, 1);
                float y  = __shfl_xor(b1 ? a2 : a3, 1);
                float na = (b1 ? a1 : a0) + x;
                float nb = (b1 ? a3 : a2) + y;
                float z  = __shfl_xor(b2 ? na : nb, 2);
                float nc = (b2 ? nb : na) + z;
                nc += __shfl_xor(nc, 4);
                nc += __shfl_xor(nc, 8);
                nc += __shfl_xor(nc, 16);
                nc += __shfl_xor(nc, 32);
                float g1 = __shfl_xor(nc, 1);       // gate q^1
                float g2 = __shfl_xor(nc, 2);       // gate q^2
                float g3 = __shfl_xor(g1, 2);       // gate q^3
                // variable m holds gate q^m; gate j lives at index j^q
                a0 = b1 ? (b2 ? g3 : g1) : (b2 ? g2 : nc);   // gate 0 (i)
                a1 = b1 ? (b2 ? g2 : nc) : (b2 ? g3 : g1);   // gate 1 (f)
                a2 = b1 ? (b2 ? g1 : g3) : (b2 ? nc : g2);   // gate 2 (g)
                a3 = b1 ? (b2 ? nc : g2) : (b2 ? g1 : g3);   // gate 3 (o)
            }

            // ---- gates on all lanes (redundant, no divergence)
            float gi = a0 + xg0, gf = a1 + xg1, gG = a2 + xg2, go = a3 + xg3;
            float cn = sigm_f(gf) * creg + sigm_f(gi) * tanh_f(gG);
            creg = cn;
            float hn = sigm_f(go) * tanh_f(cn);

            // ---- deposit in mailbox (per-wave lane 0)
            if (lam == 0) {
                uint64_t word = ((uint64_t)__float_as_uint(hn) << 32) | (uint64_t)(uint32_t)it;
                __hip_atomic_store(&mbox[w], word,
                                   __ATOMIC_RELAXED, __HIP_MEMORY_SCOPE_WORKGROUP);
            }

            // ---- wave 0 gathers + ONE coalesced 32B store into WG k's
            //      PRIVATE 128B line (sole writer)
            if (t < 4) {
                uint64_t u;
                do {
                    u = __hip_atomic_load(&mbox[t],
                                          __ATOMIC_RELAXED, __HIP_MEMORY_SCOPE_WORKGROUP);
                } while ((uint32_t)u != (uint32_t)it);
                if (l == 3)
                    hall[(size_t)step * 1024 + (k << 2) + t] =
                        __uint_as_float((uint32_t)(u >> 32));
                __hip_atomic_store(&wb[(k << 4) + t], u,
                                   __ATOMIC_RELAXED, __HIP_MEMORY_SCOPE_AGENT);
            }
        }
    }
}

extern "C" void kernel_launch(void* const* d_in, const int* in_sizes, int n_in,
                              void* d_out, int out_size, void* d_ws, size_t ws_size,
                              hipStream_t stream)
{
    const float* x      = (const float*)d_in[0];
    const int*   ts     = (const int*)d_in[1];
    const float* proj_w = (const float*)d_in[2];
    const float* proj_b = (const float*)d_in[3];
    const float* te_w1  = (const float*)d_in[4];
    const float* te_b1  = (const float*)d_in[5];
    const float* te_w2  = (const float*)d_in[6];
    const float* te_b2  = (const float*)d_in[7];
    const float* Wih    = (const float*)d_in[8];
    const float* Whh    = (const float*)d_in[9];
    const float* bih    = (const float*)d_in[10];
    const float* bhh    = (const float*)d_in[11];
    const float* lin_w  = (const float*)d_in[12];
    const float* lin_b  = (const float*)d_in[13];
    float* out = (float*)d_out;

    char* ws = (char*)d_ws;
    const size_t MB16 = (size_t)NS * DT * 4;                    // 16 MiB
    float* bufA = (float*)ws;                                   // emb -> emb2 -> hall
    float* bufB = (float*)(ws + MB16);                          // h1 -> xp
    const size_t xg_f32_bytes  = (size_t)NS * 16384 * 4;        // 256 MiB
    const size_t xg_bf16_bytes = (size_t)NS * 16384 * 2;        // 128 MiB
    const size_t hbuf_bytes    = 2 * 4096 * sizeof(uint64_t);   // 64 KiB (padded lines)
    const bool use_f32_xg = ws_size >= 2 * MB16 + xg_f32_bytes + hbuf_bytes + 64;
    float*          XGf = (float*)(ws + 2 * MB16);
    __hip_bfloat16* XGb = (__hip_bfloat16*)(ws + 2 * MB16);
    uint64_t* hbuf = (uint64_t*)(ws + 2 * MB16 +
                                 (use_f32_xg ? xg_f32_bytes : xg_bf16_bytes));

    hipMemsetAsync(hbuf, 0, hbuf_bytes, stream);

    // emb = sinusoidal(timesteps)
    emb_kernel<<<NS, 512, 0, stream>>>(ts, bufA);
    // h1 = silu(emb @ te_w1^T + te_b1)
    gemm_bt<true, false, 0><<<dim3(16, 32), 256, 0, stream>>>(
        bufA, te_w1, te_b1, nullptr, nullptr, bufB, nullptr, NS, DT, DT);
    // emb2 = h1 @ te_w2^T + te_b2
    gemm_bt<false, false, 0><<<dim3(16, 32), 256, 0, stream>>>(
        bufB, te_w2, te_b2, nullptr, nullptr, bufA, nullptr, NS, DT, DT);
    // xp = x @ proj_w^T + proj_b + emb2
    gemm_bt<false, true, 0><<<dim3(16, 32), 256, 0, stream>>>(
        x, proj_w, proj_b, nullptr, bufA, bufB, nullptr, NS, DT, DT);
    // XG[l] = xp @ Wih[l]^T + bih[l] + bhh[l]   (permuted layout), z = layer
    if (use_f32_xg) {
        gemm_bt<false, false, 2><<<dim3(64, 32, 4), 256, 0, stream>>>(
            bufB, Wih, bih, bhh, nullptr, XGf, nullptr, NS, H4, DT);
        seq_kernel<float><<<256, 256, 0, stream>>>(Whh, XGf, bufA, hbuf);
    } else {
        gemm_bt<false, false, 1><<<dim3(64, 32, 4), 256, 0, stream>>>(
            bufB, Wih, bih, bhh, nullptr, nullptr, XGb, NS, H4, DT);
        seq_kernel<__hip_bfloat16><<<256, 256, 0, stream>>>(Whh, XGb, bufA, hbuf);
    }
    // out = hall @ lin_w^T + lin_b
    gemm_bt<false, false, 0><<<dim3(16, 32), 256, 0, stream>>>(
        bufA, lin_w, lin_b, nullptr, nullptr, out, nullptr, NS, DT, DT);
}

// Round 9
// 41559.537 us; speedup vs baseline: 2.7449x; 1.1096x over previous
//
#include <hip/hip_runtime.h>
#include <hip/hip_bf16.h>
#include <stdint.h>

#define NS 4096     // samples / time steps
#define DT 1024     // dim_t == hidden == in
#define H4 4096     // 4*HID

// ---------- math helpers ----------
__device__ __forceinline__ float sigm_f(float x) { return 1.f / (1.f + __expf(-x)); }
__device__ __forceinline__ float tanh_f(float x) {
    float ax = fminf(fabsf(x), 15.f);                 // overflow-safe
    float t = 1.f - 2.f / (__expf(2.f * ax) + 1.f);
    return copysignf(t, x);
}

// ---------- sinusoidal embedding ----------
__global__ void emb_kernel(const int* __restrict__ ts, float* __restrict__ emb) {
    int t = blockIdx.x;
    int i = threadIdx.x;                 // 0..511
    float tv = (float)ts[t];
    const float c = -0.018024149455922082f;  // -ln(10000)/511
    float f = __expf(c * (float)i);
    float a = tv * f;
    float s, co;
    sincosf(a, &s, &co);
    emb[(size_t)t * DT + i] = s;
    emb[(size_t)t * DT + 512 + i] = co;
}

// ---------- generic C = A(M,K) @ B(Nc,K)^T + bias [+bias2] [+skip] [silu] ----------
// BM=128, BN=64, BK=16, 256 threads, each thread 8x4 outputs.
// XGMODE: 0 = plain fp32 C; 1 = bf16 XG layout; 2 = fp32 XG layout.
// XG layout per epoch (4096 elems): pos = k*16 + r*4 + q for col = q*1024 + 4k + r.
template <bool SILU, bool SKIP, int XGMODE>
__global__ __launch_bounds__(256) void gemm_bt(
    const float* __restrict__ A, const float* __restrict__ B,
    const float* __restrict__ bias, const float* __restrict__ bias2,
    const float* __restrict__ skip, float* __restrict__ Cf,
    __hip_bfloat16* __restrict__ Cb, int M, int Nc, int K)
{
    __shared__ __align__(16) float As[16][132];
    __shared__ __align__(16) float Bs[16][68];
    const int bn = blockIdx.x, bm = blockIdx.y, lz = blockIdx.z;
    if (XGMODE) {
        B     += (size_t)lz * H4 * DT;
        bias  += (size_t)lz * H4;
        bias2 += (size_t)lz * H4;
    }
    const int tid = threadIdx.x;
    const int tr = tid >> 4, tc = tid & 15;
    const int alr = tid >> 1, alc = (tid & 1) << 3;   // A: 128 rows x 16 cols
    const int blr = tid >> 2, blc = (tid & 3) << 2;   // B: 64 rows x 16 cols
    const float* Ap = A + (size_t)(bm * 128 + alr) * K + alc;
    const float* Bp = B + (size_t)(bn * 64 + blr) * K + blc;

    float acc[8][4];
#pragma unroll
    for (int i = 0; i < 8; i++)
#pragma unroll
        for (int j = 0; j < 4; j++) acc[i][j] = 0.f;

    for (int kk = 0; kk < K; kk += 16) {
        float4 a0 = *(const float4*)(Ap + kk);
        float4 a1 = *(const float4*)(Ap + kk + 4);
        float4 b0 = *(const float4*)(Bp + kk);
        __syncthreads();
        As[alc + 0][alr] = a0.x; As[alc + 1][alr] = a0.y;
        As[alc + 2][alr] = a0.z; As[alc + 3][alr] = a0.w;
        As[alc + 4][alr] = a1.x; As[alc + 5][alr] = a1.y;
        As[alc + 6][alr] = a1.z; As[alc + 7][alr] = a1.w;
        Bs[blc + 0][blr] = b0.x; Bs[blc + 1][blr] = b0.y;
        Bs[blc + 2][blr] = b0.z; Bs[blc + 3][blr] = b0.w;
        __syncthreads();
#pragma unroll
        for (int k = 0; k < 16; k++) {
            const float4 av0 = *(const float4*)&As[k][tr * 8];
            const float4 av1 = *(const float4*)&As[k][tr * 8 + 4];
            const float4 bv  = *(const float4*)&Bs[k][tc * 4];
            float aa[8] = {av0.x, av0.y, av0.z, av0.w, av1.x, av1.y, av1.z, av1.w};
            float bb[4] = {bv.x, bv.y, bv.z, bv.w};
#pragma unroll
            for (int i = 0; i < 8; i++)
#pragma unroll
                for (int j = 0; j < 4; j++)
                    acc[i][j] = fmaf(aa[i], bb[j], acc[i][j]);
        }
    }

#pragma unroll
    for (int i = 0; i < 8; i++) {
        int row = bm * 128 + tr * 8 + i;
#pragma unroll
        for (int j = 0; j < 4; j++) {
            int col = bn * 64 + tc * 4 + j;
            float v = acc[i][j] + bias[col];
            if (XGMODE) v += bias2[col];
            if (SKIP)   v += skip[(size_t)row * Nc + col];
            if (SILU)   v = v * (1.f / (1.f + __expf(-v)));
            if (XGMODE) {
                int q = col >> 10, jj = col & 1023;
                size_t idx = (size_t)row * 16384 + (size_t)lz * 4096
                           + ((size_t)(jj >> 2) << 4) + ((jj & 3) << 2) + q;
                if (XGMODE == 2) Cf[idx] = v;
                else             Cb[idx] = __float2bfloat16(v);
            } else {
                Cf[(size_t)row * Nc + col] = v;
            }
        }
    }
}

// ---------- persistent sequential LSTM chain ----------
// ROUND-0 STRUCTURE (best measured: 40.0ms seq) + r7's private-line hbuf
// (the only restructure-arc piece that measured a gain: -3.4ms on r5 base).
// 256 WGs x 256 threads; WG k owns h/c rows [4k,4k+4).
// Dot mapping (broadcast-optimized): lane = (j = t&15, cg = (t>>4)&3), wave w.
// Lane computes g-row d=j (r=j>>2, q=j&3, grow=q*1024+4k+r) over cols
// 256w + 64cg + [0,64). The 16 lanes sharing cg read the SAME LDS address
// -> free broadcast. Rotation (i+4cg)&15 keeps residual conflicts 2-way.
// Cross-wave reduce via 64-float lds_p + B2; gates+publish by threads t<4 of
// wave 0 -> one coalesced 32B store.
// PRIVATE-LINE hbuf [2][256][16] u64 (r7-verified): WG k's 4 rows occupy
// bytes 0..31 of its OWN 128B line-aligned region -> sole writer per line,
// no cross-XCD same-line write interleave (r2 calibration: ~700cy per
// serialized same-line transaction). Poll word for row m*256+t:
// (m<<10) + ((t>>2)<<4) + (t&3).
// Evidence trail: r2 bank conflicts free (same-addr broadcast); r3 publish
// coalescing verified via WRITE_SIZE; r5 poll-rate and fold both null;
// r6 1024-thread blocked by regsPerBlock=131072 (128 VGPR cap); r7
// private lines -3.4ms. The r2 wave-local structure itself never beat r0
// -> reverted to r0 structure here.
// Deadlock-free: slot for epoch e is only overwritten at e+2, which requires
// all WGs published e+1, which requires all WGs consumed e.
template <typename XT>
__global__ __launch_bounds__(256, 1) void seq_kernel(
    const float* __restrict__ Whh,            // [4][4096][1024]
    const XT* __restrict__ XG,                // [epoch][k*16 + r*4 + q]
    float* __restrict__ hall,                 // [4096][1024]
    uint64_t* hbuf)                           // [2][256][16]
{
    const int k = blockIdx.x;
    const int t = threadIdx.x;
    const int j = t & 15;                     // g-row index d
    const int cg = (t >> 4) & 3;              // 64-col sub-chunk
    const int w = t >> 6;                     // wave id
    const int q = j & 3, r = j >> 2;
    const int grow = q * 1024 + 4 * k + r;

    // weights, rotated to match the rotated LDS reads:
    // wreg[l][i*4+e] = Whh[l][grow][256w + 64cg + 4*((i+4cg)&15) + e]
    float wreg[4][64];
#pragma unroll
    for (int l = 0; l < 4; l++) {
        const float* src = Whh + ((size_t)l * H4 + grow) * 1024 + (w << 8) + (cg << 6);
#pragma unroll
        for (int i = 0; i < 16; i++) {
            int ii = (i + 4 * cg) & 15;
            float4 v = *(const float4*)(src + (ii << 2));
            wreg[l][i * 4 + 0] = v.x; wreg[l][i * 4 + 1] = v.y;
            wreg[l][i * 4 + 2] = v.z; wreg[l][i * 4 + 3] = v.w;
        }
    }

    __shared__ __align__(16) float lh[1024];
    __shared__ __align__(16) float lds_p[64];
    float creg = 0.f;   // c for row 4k+t (threads t<4 only)

    // poll word index for m-th staged row (row = m*256 + t):
    //   line = (m<<6)+(t>>2), slot = t&3 -> word (m<<10) + ((t>>2)<<4) + (t&3)
    const int pw = ((t >> 2) << 4) + (t & 3);

    for (int step = 0; step < NS; ++step) {
#pragma unroll
        for (int l = 0; l < 4; l++) {
            const int it = step * 4 + l + 1;             // epoch being produced
            const uint32_t rtag = (uint32_t)(it - 1);
            uint64_t* rb = (l & 1) ? (hbuf + 4096) : hbuf;        // (it-1)&1 == l&1
            uint64_t* wb = ((l + 1) & 1) ? (hbuf + 4096) : hbuf;  // it&1

            // ---- XG prefetch by gate threads, issued BEFORE polling
            float xg0 = 0.f, xg1 = 0.f, xg2 = 0.f, xg3 = 0.f;
            if (t < 4) {
                const XT* p = XG + (size_t)(it - 1) * H4 + (k << 4) + (t << 2);
                if constexpr (sizeof(XT) == 4) {
                    float4 v = *(const float4*)p;
                    xg0 = v.x; xg1 = v.y; xg2 = v.z; xg3 = v.w;
                } else {
                    ushort4 v = *(const ushort4*)p;
                    xg0 = __uint_as_float((uint32_t)v.x << 16);
                    xg1 = __uint_as_float((uint32_t)v.y << 16);
                    xg2 = __uint_as_float((uint32_t)v.z << 16);
                    xg3 = __uint_as_float((uint32_t)v.w << 16);
                }
            }

            // ---- poll + stage (thread t owns rows t, 256+t, 512+t, 768+t)
            uint32_t got = 0;
            while (got != 0xFu) {
#pragma unroll
                for (int m = 0; m < 4; m++) {
                    if (!(got & (1u << m))) {
                        uint64_t u = __hip_atomic_load(&rb[(m << 10) + pw],
                                                       __ATOMIC_RELAXED, __HIP_MEMORY_SCOPE_AGENT);
                        if ((uint32_t)u == rtag) {
                            lh[(m << 8) + t] = __uint_as_float((uint32_t)(u >> 32));
                            got |= (1u << m);
                        }
                    }
                }
            }
            __syncthreads();   // B1: lh complete

            // ---- broadcast dot: 16 lanes/address, rotated, 4 accumulators
            const float* hbase = lh + (w << 8) + (cg << 6);
            float a0 = 0.f, a1 = 0.f, a2 = 0.f, a3 = 0.f;
#pragma unroll
            for (int i = 0; i < 16; i++) {
                int ii = (i + 4 * cg) & 15;
                const float4 hv = *(const float4*)(hbase + (ii << 2));
                a0 = fmaf(wreg[l][i * 4 + 0], hv.x, a0);
                a1 = fmaf(wreg[l][i * 4 + 1], hv.y, a1);
                a2 = fmaf(wreg[l][i * 4 + 2], hv.z, a2);
                a3 = fmaf(wreg[l][i * 4 + 3], hv.w, a3);
            }
            float acc = (a0 + a1) + (a2 + a3);
            // reduce the 4 cg-chunks (lanes j, j+16, j+32, j+48)
            acc += __shfl_xor(acc, 16);
            acc += __shfl_xor(acc, 32);
            if ((t & 63) < 16) lds_p[(j << 2) + w] = acc;   // [j][w]
            __syncthreads();   // B2: lds_p complete

            if (t < 4) {
                // g[q] for hidden row 4k+t: sum lds_p[(t*4+q)*4 + w] over w
                const float4 p0 = *(const float4*)&lds_p[(t << 4) + 0];
                const float4 p1 = *(const float4*)&lds_p[(t << 4) + 4];
                const float4 p2 = *(const float4*)&lds_p[(t << 4) + 8];
                const float4 p3 = *(const float4*)&lds_p[(t << 4) + 12];
                float gi = (p0.x + p0.y) + (p0.z + p0.w) + xg0;
                float gf = (p1.x + p1.y) + (p1.z + p1.w) + xg1;
                float gG = (p2.x + p2.y) + (p2.z + p2.w) + xg2;
                float go = (p3.x + p3.y) + (p3.z + p3.w) + xg3;
                float cn = sigm_f(gf) * creg + sigm_f(gi) * tanh_f(gG);
                creg = cn;
                float hn = sigm_f(go) * tanh_f(cn);
                if (l == 3) hall[(size_t)step * 1024 + (k << 2) + t] = hn;
                uint64_t word = ((uint64_t)__float_as_uint(hn) << 32) | (uint64_t)(uint32_t)it;
                // private-line publish: WG k's 128B line, words (k<<4)+0..3
                __hip_atomic_store(&wb[(k << 4) + t], word,
                                   __ATOMIC_RELAXED, __HIP_MEMORY_SCOPE_AGENT);
            }
        }
    }
}

extern "C" void kernel_launch(void* const* d_in, const int* in_sizes, int n_in,
                              void* d_out, int out_size, void* d_ws, size_t ws_size,
                              hipStream_t stream)
{
    const float* x      = (const float*)d_in[0];
    const int*   ts     = (const int*)d_in[1];
    const float* proj_w = (const float*)d_in[2];
    const float* proj_b = (const float*)d_in[3];
    const float* te_w1  = (const float*)d_in[4];
    const float* te_b1  = (const float*)d_in[5];
    const float* te_w2  = (const float*)d_in[6];
    const float* te_b2  = (const float*)d_in[7];
    const float* Wih    = (const float*)d_in[8];
    const float* Whh    = (const float*)d_in[9];
    const float* bih    = (const float*)d_in[10];
    const float* bhh    = (const float*)d_in[11];
    const float* lin_w  = (const float*)d_in[12];
    const float* lin_b  = (const float*)d_in[13];
    float* out = (float*)d_out;

    char* ws = (char*)d_ws;
    const size_t MB16 = (size_t)NS * DT * 4;                    // 16 MiB
    float* bufA = (float*)ws;                                   // emb -> emb2 -> hall
    float* bufB = (float*)(ws + MB16);                          // h1 -> xp
    const size_t xg_f32_bytes  = (size_t)NS * 16384 * 4;        // 256 MiB
    const size_t xg_bf16_bytes = (size_t)NS * 16384 * 2;        // 128 MiB
    const size_t hbuf_bytes    = 2 * 4096 * sizeof(uint64_t);   // 64 KiB (private lines)
    const bool use_f32_xg = ws_size >= 2 * MB16 + xg_f32_bytes + hbuf_bytes + 64;
    float*          XGf = (float*)(ws + 2 * MB16);
    __hip_bfloat16* XGb = (__hip_bfloat16*)(ws + 2 * MB16);
    uint64_t* hbuf = (uint64_t*)(ws + 2 * MB16 +
                                 (use_f32_xg ? xg_f32_bytes : xg_bf16_bytes));

    hipMemsetAsync(hbuf, 0, hbuf_bytes, stream);

    // emb = sinusoidal(timesteps)
    emb_kernel<<<NS, 512, 0, stream>>>(ts, bufA);
    // h1 = silu(emb @ te_w1^T + te_b1)
    gemm_bt<true, false, 0><<<dim3(16, 32), 256, 0, stream>>>(
        bufA, te_w1, te_b1, nullptr, nullptr, bufB, nullptr, NS, DT, DT);
    // emb2 = h1 @ te_w2^T + te_b2
    gemm_bt<false, false, 0><<<dim3(16, 32), 256, 0, stream>>>(
        bufB, te_w2, te_b2, nullptr, nullptr, bufA, nullptr, NS, DT, DT);
    // xp = x @ proj_w^T + proj_b + emb2
    gemm_bt<false, true, 0><<<dim3(16, 32), 256, 0, stream>>>(
        x, proj_w, proj_b, nullptr, bufA, bufB, nullptr, NS, DT, DT);
    // XG[l] = xp @ Wih[l]^T + bih[l] + bhh[l]   (permuted layout), z = layer
    if (use_f32_xg) {
        gemm_bt<false, false, 2><<<dim3(64, 32, 4), 256, 0, stream>>>(
            bufB, Wih, bih, bhh, nullptr, XGf, nullptr, NS, H4, DT);
        seq_kernel<float><<<256, 256, 0, stream>>>(Whh, XGf, bufA, hbuf);
    } else {
        gemm_bt<false, false, 1><<<dim3(64, 32, 4), 256, 0, stream>>>(
            bufB, Wih, bih, bhh, nullptr, nullptr, XGb, NS, H4, DT);
        seq_kernel<__hip_bfloat16><<<256, 256, 0, stream>>>(Whh, XGb, bufA, hbuf);
    }
    // out = hall @ lin_w^T + lin_b
    gemm_bt<false, false, 0><<<dim3(16, 32), 256, 0, stream>>>(
        bufA, lin_w, lin_b, nullptr, nullptr, out, nullptr, NS, DT, DT);
}